// Round 2
// baseline (5856.651 us; speedup 1.0000x reference)
//
#include <hip/hip_runtime.h>
#include <hip/hip_bf16.h>

#define Bdim 256
#define Sdim 256
#define Hdim 1024
#define Vdim 128

#define NGRP 8    // batch groups (one per XCD if round-robin)
#define MB   32   // batch rows per group
#define NBLK 32   // blocks per group
#define NB   32   // neurons per block
#define VB   4    // vocab outputs per block (128/32)
#define FPAD 64   // ints per flag (256B line padding)

typedef __attribute__((ext_vector_type(8))) short short8;
typedef __attribute__((ext_vector_type(4))) float floatx4;

#define MFMA_BF16(a, b, c) __builtin_amdgcn_mfma_f32_16x16x32_bf16((a), (b), (c), 0, 0, 0)

__device__ __forceinline__ unsigned short f2bf(float f) {
  union { float f; unsigned u; } v; v.f = f;
  unsigned r = v.u + 0x7fffu + ((v.u >> 16) & 1u);
  return (unsigned short)(r >> 16);
}
__device__ __forceinline__ float bf2f(unsigned short s) {
  union { unsigned u; float f; } v; v.u = ((unsigned)s) << 16;
  return v.f;
}
// split 8 consecutive floats (two float4) into bf16 hi + residual lo fragments
__device__ __forceinline__ void split8(floatx4 a, floatx4 b, short8& hi, short8& lo) {
#pragma unroll
  for (int e = 0; e < 4; ++e) {
    unsigned short h0 = f2bf(a[e]);
    hi[e] = (short)h0;
    lo[e] = (short)f2bf(a[e] - bf2f(h0));
    unsigned short h1 = f2bf(b[e]);
    hi[e + 4] = (short)h1;
    lo[e + 4] = (short)f2bf(b[e] - bf2f(h1));
  }
}

// E2[v][k] = sum_h embed[v][h] * Wxh[k][h]   (128 x 1024), near-fp32 via hi/lo split
__global__ __launch_bounds__(64) void e2_kernel(const float* __restrict__ embed,
                                                const float* __restrict__ Wxh,
                                                float* __restrict__ E2) {
  const int lane = threadIdx.x;
  const int quad = lane >> 4, l16 = lane & 15;
  const int n0 = blockIdx.x * 16;  // k-slice of E2
  floatx4 acc[8] = {};
  for (int ki = 0; ki < 32; ++ki) {
    const int k0 = ki * 32 + quad * 8;
    const float* bp = Wxh + (size_t)(n0 + l16) * Hdim + k0;
    floatx4 b0 = *(const floatx4*)bp;
    floatx4 b1 = *(const floatx4*)(bp + 4);
    short8 bhi, blo;
    split8(b0, b1, bhi, blo);
#pragma unroll
    for (int mi = 0; mi < 8; ++mi) {
      const float* ap = embed + (size_t)(mi * 16 + l16) * Hdim + k0;
      floatx4 a0 = *(const floatx4*)ap;
      floatx4 a1 = *(const floatx4*)(ap + 4);
      short8 ahi, alo;
      split8(a0, a1, ahi, alo);
      acc[mi] = MFMA_BF16(ahi, bhi, acc[mi]);
      acc[mi] = MFMA_BF16(ahi, blo, acc[mi]);
      acc[mi] = MFMA_BF16(alo, bhi, acc[mi]);
    }
  }
#pragma unroll
  for (int mi = 0; mi < 8; ++mi)
#pragma unroll
    for (int r = 0; r < 4; ++r)
      E2[(size_t)(mi * 16 + quad * 4 + r) * Hdim + n0 + l16] = acc[mi][r];
}

__global__ __launch_bounds__(256) void rnn_kernel(
    const int* __restrict__ xg, const float* __restrict__ Whh,
    const float* __restrict__ Wxh_b, const float* __restrict__ Whh_b,
    const float* __restrict__ fc_w, const float* __restrict__ fc_b,
    const float* __restrict__ E2, unsigned short* __restrict__ hbuf,
    int* __restrict__ flags, float* __restrict__ dout) {
  __shared__ float e2s[Vdim][NB + 1];      // E2 slice, fp32
  __shared__ float redc[4][MB][NB + 1];    // cross-wave K-reduction (recurrence)
  __shared__ float redf[4][MB][17];        // cross-wave K-reduction (fc)
  __shared__ unsigned short fcs[VB][Hdim + 8];  // fc_w slice, bf16
  __shared__ float bias2[NB];
  __shared__ int xi[MB];

  const int tid = threadIdx.x;
  const int w = tid >> 6, lane = tid & 63;
  const int quad = lane >> 4, l16 = lane & 15;
  const int bid = blockIdx.x;
  const int g = bid & 7, j = bid >> 3;
  const int r0 = g * MB;   // batch rows
  const int n0 = j * NB;   // neuron slice
  const int v0 = j * VB;   // vocab slice
  int* gflags = flags + g * NBLK * FPAD;   // this group's 32 flags (256B apart)
  int* myflag = gflags + j * FPAD;

  // ---- preload Whh slice as hi/lo bf16 MFMA fragments in registers (reused 256 steps) ----
  short8 Bhi[2][8], Blo[2][8];
#pragma unroll
  for (int ni = 0; ni < 2; ++ni)
#pragma unroll
    for (int ki = 0; ki < 8; ++ki) {
      const int n = n0 + ni * 16 + l16;
      const int k0 = w * 256 + ki * 32 + quad * 8;
      const float* p = Whh + (size_t)n * Hdim + k0;
      floatx4 f0 = *(const floatx4*)p;
      floatx4 f1 = *(const floatx4*)(p + 4);
      split8(f0, f1, Bhi[ni][ki], Blo[ni][ki]);
    }
  // fc_w slice -> LDS (bf16; last layer, no error amplification)
  for (int i = tid; i < VB * Hdim; i += 256) {
    int r = i >> 10, c = i & (Hdim - 1);
    fcs[r][c] = f2bf(fc_w[(size_t)(v0 + r) * Hdim + c]);
  }
  // E2 slice -> LDS (fp32)
  for (int i = tid; i < Vdim * NB; i += 256) {
    int v = i >> 5, nl = i & 31;
    e2s[v][nl] = E2[(size_t)v * Hdim + n0 + nl];
  }
  if (tid < NB) bias2[tid] = Wxh_b[n0 + tid] + Whh_b[n0 + tid];

  unsigned short* hb0 = hbuf;
  unsigned short* hb1 = hbuf + (size_t)Bdim * Hdim;

#pragma unroll 1
  for (int t = 0; t <= Sdim; ++t) {
    if (t < Sdim && tid < MB) xi[tid] = xg[(size_t)(r0 + tid) * Sdim + t];

    // ---- wait: all group blocks must have published h_{t-1} (flag >= t) ----
    if (t >= 1 && w == 0) {
      const int target = t;
      for (;;) {
        int v = (lane < NBLK)
                    ? __hip_atomic_load(gflags + lane * FPAD, __ATOMIC_RELAXED,
                                        __HIP_MEMORY_SCOPE_AGENT)
                    : target;
        if (__all(v >= target)) break;
        __builtin_amdgcn_s_sleep(2);
      }
    }
    __syncthreads();
    if (t >= 1) __threadfence();  // acquire: invalidate caches before reading h

    if (t >= 1) {
      const unsigned short* hp = ((t - 1) & 1) ? hb1 : hb0;
      const bool recc = (t < Sdim);
      floatx4 accr[2][2] = {};
      floatx4 accf[2] = {};
      const unsigned short* hrow0 = hp + (size_t)(r0 + l16) * Hdim;
      const unsigned short* hrow1 = hp + (size_t)(r0 + 16 + l16) * Hdim;
#pragma unroll
      for (int ki = 0; ki < 8; ++ki) {
        const int k0 = w * 256 + ki * 32 + quad * 8;
        short8 a0 = *(const short8*)(hrow0 + k0);
        short8 a1 = *(const short8*)(hrow1 + k0);
        if (recc) {
          accr[0][0] = MFMA_BF16(a0, Bhi[0][ki], accr[0][0]);
          accr[0][0] = MFMA_BF16(a0, Blo[0][ki], accr[0][0]);
          accr[1][0] = MFMA_BF16(a1, Bhi[0][ki], accr[1][0]);
          accr[1][0] = MFMA_BF16(a1, Blo[0][ki], accr[1][0]);
          accr[0][1] = MFMA_BF16(a0, Bhi[1][ki], accr[0][1]);
          accr[0][1] = MFMA_BF16(a0, Blo[1][ki], accr[0][1]);
          accr[1][1] = MFMA_BF16(a1, Bhi[1][ki], accr[1][1]);
          accr[1][1] = MFMA_BF16(a1, Blo[1][ki], accr[1][1]);
        }
        short8 bf = *(const short8*)(&fcs[l16 & 3][k0]);  // cols 4..15 unused
        accf[0] = MFMA_BF16(a0, bf, accf[0]);
        accf[1] = MFMA_BF16(a1, bf, accf[1]);
      }
      if (recc) {
#pragma unroll
        for (int mi = 0; mi < 2; ++mi)
#pragma unroll
          for (int ni = 0; ni < 2; ++ni)
#pragma unroll
            for (int r = 0; r < 4; ++r)
              redc[w][mi * 16 + quad * 4 + r][ni * 16 + l16] = accr[mi][ni][r];
      }
#pragma unroll
      for (int mi = 0; mi < 2; ++mi)
#pragma unroll
        for (int r = 0; r < 4; ++r)
          redf[w][mi * 16 + quad * 4 + r][l16] = accf[mi][r];
    }
    __syncthreads();

    // epilogue: h_t = tanh(E2[x] + bias + h@Whh^T)
    if (t < Sdim) {
      unsigned short* hw = (t & 1) ? hb1 : hb0;
      for (int i = tid; i < MB * NB; i += 256) {
        int m = i >> 5, nl = i & 31;
        float s = e2s[xi[m]][nl] + bias2[nl];
        if (t >= 1)
          s += redc[0][m][nl] + redc[1][m][nl] + redc[2][m][nl] + redc[3][m][nl];
        float hv = tanhf(s);
        hw[(size_t)(r0 + m) * Hdim + n0 + nl] = f2bf(hv);
        if (t == Sdim - 1)
          dout[(size_t)Bdim * Sdim * Vdim + (size_t)(r0 + m) * Hdim + n0 + nl] = hv;
      }
    }
    // publish h_t: drain writes (syncthreads) then release-store my flag
    if (t < Sdim) {
      __syncthreads();
      if (tid == 0)
        __hip_atomic_store(myflag, t + 1, __ATOMIC_RELEASE, __HIP_MEMORY_SCOPE_AGENT);
    }
    // out[:, t-1, v-slice] = h_{t-1} @ fc^T + fc_b  (local data, after signal)
    if (t >= 1 && tid < MB * VB) {
      int m = tid >> 2, vv = tid & 3;
      float o = redf[0][m][vv] + redf[1][m][vv] + redf[2][m][vv] + redf[3][m][vv] + fc_b[v0 + vv];
      dout[((size_t)(r0 + m) * Sdim + (t - 1)) * Vdim + v0 + vv] = o;
    }
  }
}

extern "C" void kernel_launch(void* const* d_in, const int* in_sizes, int n_in,
                              void* d_out, int out_size, void* d_ws, size_t ws_size,
                              hipStream_t stream) {
  const int* x = (const int*)d_in[0];
  const float* embed = (const float*)d_in[1];
  const float* Wxh_w = (const float*)d_in[2];
  const float* Wxh_b = (const float*)d_in[3];
  const float* Whh_w = (const float*)d_in[4];
  const float* Whh_b = (const float*)d_in[5];
  const float* fc_w = (const float*)d_in[6];
  const float* fc_b = (const float*)d_in[7];
  float* out = (float*)d_out;

  char* ws = (char*)d_ws;
  float* E2 = (float*)ws;                                   // 512 KB
  unsigned short* hbuf = (unsigned short*)(ws + 524288);    // 1 MB (2 x B x H bf16)
  int* flags = (int*)(ws + 1572864);                        // 256 flags x 256B = 64 KB

  hipMemsetAsync(flags, 0, 256 * FPAD * sizeof(int), stream);
  e2_kernel<<<dim3(Hdim / 16), dim3(64), 0, stream>>>(embed, Wxh_w, E2);
  rnn_kernel<<<dim3(256), dim3(256), 0, stream>>>(x, Whh_w, Wxh_b, Whh_b, fc_w,
                                                  fc_b, E2, hbuf, flags, out);
}

// Round 3
// 1601.608 us; speedup vs baseline: 3.6567x; 3.6567x over previous
//
#include <hip/hip_runtime.h>
#include <hip/hip_bf16.h>

#define Bdim 256
#define Sdim 256
#define Hdim 1024
#define Vdim 128

#define NGRP 8    // batch groups (one per XCD if round-robin)
#define MB   32   // batch rows per group
#define NBLK 32   // blocks per group
#define NB   32   // neurons per block
#define VB   4    // vocab outputs per block (128/32)
#define FPAD 64   // ints per flag (256B line padding)

typedef __attribute__((ext_vector_type(8))) short short8;
typedef __attribute__((ext_vector_type(4))) float floatx4;

#define MFMA_BF16(a, b, c) __builtin_amdgcn_mfma_f32_16x16x32_bf16((a), (b), (c), 0, 0, 0)

__device__ __forceinline__ unsigned short f2bf(float f) {
  union { float f; unsigned u; } v; v.f = f;
  unsigned r = v.u + 0x7fffu + ((v.u >> 16) & 1u);
  return (unsigned short)(r >> 16);
}
__device__ __forceinline__ float bf2f(unsigned short s) {
  union { unsigned u; float f; } v; v.u = ((unsigned)s) << 16;
  return v.f;
}
// split 8 consecutive floats (two float4) into bf16 hi + residual lo fragments
__device__ __forceinline__ void split8(floatx4 a, floatx4 b, short8& hi, short8& lo) {
#pragma unroll
  for (int e = 0; e < 4; ++e) {
    unsigned short h0 = f2bf(a[e]);
    hi[e] = (short)h0;
    lo[e] = (short)f2bf(a[e] - bf2f(h0));
    unsigned short h1 = f2bf(b[e]);
    hi[e + 4] = (short)h1;
    lo[e + 4] = (short)f2bf(b[e] - bf2f(h1));
  }
}

// agent-scope relaxed 8B load: bypasses (possibly stale) per-XCD L2, reads IC
__device__ __forceinline__ unsigned long long ic_load(const unsigned short* p) {
  return __hip_atomic_load((const unsigned long long*)p, __ATOMIC_RELAXED,
                           __HIP_MEMORY_SCOPE_AGENT);
}
// agent-scope relaxed 8B store: write-through to IC, leaves no dirty L2 line
__device__ __forceinline__ void ic_store(unsigned short* p, unsigned long long v) {
  __hip_atomic_store((unsigned long long*)p, v, __ATOMIC_RELAXED,
                     __HIP_MEMORY_SCOPE_AGENT);
}

// E2[v][k] = sum_h embed[v][h] * Wxh[k][h]   (128 x 1024), near-fp32 via hi/lo split
__global__ __launch_bounds__(64) void e2_kernel(const float* __restrict__ embed,
                                                const float* __restrict__ Wxh,
                                                float* __restrict__ E2) {
  const int lane = threadIdx.x;
  const int quad = lane >> 4, l16 = lane & 15;
  const int n0 = blockIdx.x * 16;  // k-slice of E2
  floatx4 acc[8] = {};
  for (int ki = 0; ki < 32; ++ki) {
    const int k0 = ki * 32 + quad * 8;
    const float* bp = Wxh + (size_t)(n0 + l16) * Hdim + k0;
    floatx4 b0 = *(const floatx4*)bp;
    floatx4 b1 = *(const floatx4*)(bp + 4);
    short8 bhi, blo;
    split8(b0, b1, bhi, blo);
#pragma unroll
    for (int mi = 0; mi < 8; ++mi) {
      const float* ap = embed + (size_t)(mi * 16 + l16) * Hdim + k0;
      floatx4 a0 = *(const floatx4*)ap;
      floatx4 a1 = *(const floatx4*)(ap + 4);
      short8 ahi, alo;
      split8(a0, a1, ahi, alo);
      acc[mi] = MFMA_BF16(ahi, bhi, acc[mi]);
      acc[mi] = MFMA_BF16(ahi, blo, acc[mi]);
      acc[mi] = MFMA_BF16(alo, bhi, acc[mi]);
    }
  }
#pragma unroll
  for (int mi = 0; mi < 8; ++mi)
#pragma unroll
    for (int r = 0; r < 4; ++r)
      E2[(size_t)(mi * 16 + quad * 4 + r) * Hdim + n0 + l16] = acc[mi][r];
}

__global__ __launch_bounds__(256) void rnn_kernel(
    const int* __restrict__ xg, const float* __restrict__ Whh,
    const float* __restrict__ Wxh_b, const float* __restrict__ Whh_b,
    const float* __restrict__ fc_w, const float* __restrict__ fc_b,
    const float* __restrict__ E2, unsigned short* __restrict__ hbuf,
    int* __restrict__ flags, float* __restrict__ dout) {
  __shared__ float e2s[Vdim][NB + 1];      // E2 slice, fp32
  __shared__ float redc[4][MB][NB + 1];    // cross-wave K-reduction (recurrence)
  __shared__ float redf[4][MB][17];        // cross-wave K-reduction (fc)
  __shared__ unsigned short fcs[VB][Hdim + 8];  // fc_w slice, bf16
  __shared__ float bias2[NB];
  __shared__ int xi[MB];

  const int tid = threadIdx.x;
  const int w = tid >> 6, lane = tid & 63;
  const int quad = lane >> 4, l16 = lane & 15;
  const int bid = blockIdx.x;
  const int g = bid & 7, j = bid >> 3;
  const int r0 = g * MB;   // batch rows
  const int n0 = j * NB;   // neuron slice
  const int v0 = j * VB;   // vocab slice
  int* gflags = flags + g * NBLK * FPAD;   // this group's 32 flags (256B apart)
  int* myflag = gflags + j * FPAD;

  // ---- preload Whh slice as hi/lo bf16 MFMA fragments in registers (reused 256 steps) ----
  short8 Bhi[2][8], Blo[2][8];
#pragma unroll
  for (int ni = 0; ni < 2; ++ni)
#pragma unroll
    for (int ki = 0; ki < 8; ++ki) {
      const int n = n0 + ni * 16 + l16;
      const int k0 = w * 256 + ki * 32 + quad * 8;
      const float* p = Whh + (size_t)n * Hdim + k0;
      floatx4 f0 = *(const floatx4*)p;
      floatx4 f1 = *(const floatx4*)(p + 4);
      split8(f0, f1, Bhi[ni][ki], Blo[ni][ki]);
    }
  // fc_w slice -> LDS (bf16; last layer, no error amplification)
  for (int i = tid; i < VB * Hdim; i += 256) {
    int r = i >> 10, c = i & (Hdim - 1);
    fcs[r][c] = f2bf(fc_w[(size_t)(v0 + r) * Hdim + c]);
  }
  // E2 slice -> LDS (fp32)
  for (int i = tid; i < Vdim * NB; i += 256) {
    int v = i >> 5, nl = i & 31;
    e2s[v][nl] = E2[(size_t)v * Hdim + n0 + nl];
  }
  if (tid < NB) bias2[tid] = Wxh_b[n0 + tid] + Whh_b[n0 + tid];

  unsigned short* hb0 = hbuf;
  unsigned short* hb1 = hbuf + (size_t)Bdim * Hdim;

#pragma unroll 1
  for (int t = 0; t <= Sdim; ++t) {
    if (t < Sdim && tid < MB) xi[tid] = xg[(size_t)(r0 + tid) * Sdim + t];

    // ---- wait: all group blocks must have published h_{t-1} (flag >= t) ----
    // relaxed polls only: no acquire -> no buffer_inv; h reads below bypass L2.
    if (t >= 1 && w == 0) {
      const int target = t;
      for (;;) {
        int v = (lane < NBLK)
                    ? __hip_atomic_load(gflags + lane * FPAD, __ATOMIC_RELAXED,
                                        __HIP_MEMORY_SCOPE_AGENT)
                    : target;
        if (__all(v >= target)) break;
        __builtin_amdgcn_s_sleep(1);
      }
    }
    __syncthreads();
    __atomic_signal_fence(__ATOMIC_SEQ_CST);  // compiler-only ordering, no HW op

    if (t >= 1) {
      const unsigned short* hp = ((t - 1) & 1) ? hb1 : hb0;
      const bool recc = (t < Sdim);
      floatx4 accr[2][2] = {};
      floatx4 accf[2] = {};
      const unsigned short* hrow0 = hp + (size_t)(r0 + l16) * Hdim;
      const unsigned short* hrow1 = hp + (size_t)(r0 + 16 + l16) * Hdim;
#pragma unroll
      for (int ki = 0; ki < 8; ++ki) {
        const int k0 = w * 256 + ki * 32 + quad * 8;
        union { unsigned long long q[2]; short8 s; } ua0, ua1;
        ua0.q[0] = ic_load(hrow0 + k0);
        ua0.q[1] = ic_load(hrow0 + k0 + 4);
        ua1.q[0] = ic_load(hrow1 + k0);
        ua1.q[1] = ic_load(hrow1 + k0 + 4);
        short8 a0 = ua0.s, a1 = ua1.s;
        if (recc) {
          accr[0][0] = MFMA_BF16(a0, Bhi[0][ki], accr[0][0]);
          accr[0][0] = MFMA_BF16(a0, Blo[0][ki], accr[0][0]);
          accr[1][0] = MFMA_BF16(a1, Bhi[0][ki], accr[1][0]);
          accr[1][0] = MFMA_BF16(a1, Blo[0][ki], accr[1][0]);
          accr[0][1] = MFMA_BF16(a0, Bhi[1][ki], accr[0][1]);
          accr[0][1] = MFMA_BF16(a0, Blo[1][ki], accr[0][1]);
          accr[1][1] = MFMA_BF16(a1, Bhi[1][ki], accr[1][1]);
          accr[1][1] = MFMA_BF16(a1, Blo[1][ki], accr[1][1]);
        }
        short8 bf = *(const short8*)(&fcs[l16 & 3][k0]);  // cols 4..15 unused
        accf[0] = MFMA_BF16(a0, bf, accf[0]);
        accf[1] = MFMA_BF16(a1, bf, accf[1]);
      }
      if (recc) {
#pragma unroll
        for (int mi = 0; mi < 2; ++mi)
#pragma unroll
          for (int ni = 0; ni < 2; ++ni)
#pragma unroll
            for (int r = 0; r < 4; ++r)
              redc[w][mi * 16 + quad * 4 + r][ni * 16 + l16] = accr[mi][ni][r];
      }
#pragma unroll
      for (int mi = 0; mi < 2; ++mi)
#pragma unroll
        for (int r = 0; r < 4; ++r)
          redf[w][mi * 16 + quad * 4 + r][l16] = accf[mi][r];
    }
    __syncthreads();

    // epilogue: h_t = tanh(E2[x] + bias + h@Whh^T); 4 neurons/thread, one 8B
    // write-through store each (thread -> row m = tid>>3, cols nl0..nl0+3)
    if (t < Sdim) {
      unsigned short* hw = (t & 1) ? hb1 : hb0;
      const int m = tid >> 3, nl0 = (tid & 7) * 4;
      float hv[4];
      union { unsigned short us[4]; unsigned long long q; } pk;
#pragma unroll
      for (int e = 0; e < 4; ++e) {
        int nl = nl0 + e;
        float s = e2s[xi[m]][nl] + bias2[nl];
        if (t >= 1)
          s += redc[0][m][nl] + redc[1][m][nl] + redc[2][m][nl] + redc[3][m][nl];
        hv[e] = tanhf(s);
        pk.us[e] = f2bf(hv[e]);
      }
      ic_store(hw + (size_t)(r0 + m) * Hdim + n0 + nl0, pk.q);
      if (t == Sdim - 1) {
#pragma unroll
        for (int e = 0; e < 4; ++e)
          dout[(size_t)Bdim * Sdim * Vdim + (size_t)(r0 + m) * Hdim + n0 + nl0 + e] = hv[e];
      }
    }
    // publish h_t: __syncthreads drains each wave's vmcnt(0) (write-through
    // stores acked at IC) before the barrier; then one relaxed flag store.
    if (t < Sdim) {
      __syncthreads();
      __atomic_signal_fence(__ATOMIC_SEQ_CST);
      if (tid == 0)
        __hip_atomic_store(myflag, t + 1, __ATOMIC_RELAXED, __HIP_MEMORY_SCOPE_AGENT);
    }
    // out[:, t-1, v-slice] = h_{t-1} @ fc^T + fc_b  (local data, after signal)
    if (t >= 1 && tid < MB * VB) {
      int m = tid >> 2, vv = tid & 3;
      float o = redf[0][m][vv] + redf[1][m][vv] + redf[2][m][vv] + redf[3][m][vv] + fc_b[v0 + vv];
      dout[((size_t)(r0 + m) * Sdim + (t - 1)) * Vdim + v0 + vv] = o;
    }
  }
}

extern "C" void kernel_launch(void* const* d_in, const int* in_sizes, int n_in,
                              void* d_out, int out_size, void* d_ws, size_t ws_size,
                              hipStream_t stream) {
  const int* x = (const int*)d_in[0];
  const float* embed = (const float*)d_in[1];
  const float* Wxh_w = (const float*)d_in[2];
  const float* Wxh_b = (const float*)d_in[3];
  const float* Whh_w = (const float*)d_in[4];
  const float* Whh_b = (const float*)d_in[5];
  const float* fc_w = (const float*)d_in[6];
  const float* fc_b = (const float*)d_in[7];
  float* out = (float*)d_out;

  char* ws = (char*)d_ws;
  float* E2 = (float*)ws;                                   // 512 KB
  unsigned short* hbuf = (unsigned short*)(ws + 524288);    // 1 MB (2 x B x H bf16)
  int* flags = (int*)(ws + 1572864);                        // 256 flags x 256B = 64 KB

  hipMemsetAsync(flags, 0, 256 * FPAD * sizeof(int), stream);
  e2_kernel<<<dim3(Hdim / 16), dim3(64), 0, stream>>>(embed, Wxh_w, E2);
  rnn_kernel<<<dim3(256), dim3(256), 0, stream>>>(x, Whh_w, Wxh_b, Whh_b, fc_w,
                                                  fc_b, E2, hbuf, flags, out);
}

// Round 5
// 1280.161 us; speedup vs baseline: 4.5749x; 1.2511x over previous
//
#include <hip/hip_runtime.h>
#include <hip/hip_bf16.h>

#define Bdim 256
#define Sdim 256
#define Hdim 1024
#define Vdim 128

#define NGRP 8    // batch groups
#define MB   32   // batch rows per group
#define NBLK 32   // blocks per group
#define NB   32   // neurons per block
#define VB   4    // vocab outputs per block (128/32)
#define FPAD 64   // ints per flag (256B line padding)

typedef __attribute__((ext_vector_type(8))) short short8;
typedef __attribute__((ext_vector_type(4))) float floatx4;

#define MFMA_BF16(a, b, c) __builtin_amdgcn_mfma_f32_16x16x32_bf16((a), (b), (c), 0, 0, 0)

__device__ __forceinline__ unsigned short f2bf(float f) {
  union { float f; unsigned u; } v; v.f = f;
  unsigned r = v.u + 0x7fffu + ((v.u >> 16) & 1u);
  return (unsigned short)(r >> 16);
}
__device__ __forceinline__ float bf2f(unsigned short s) {
  union { unsigned u; float f; } v; v.u = ((unsigned)s) << 16;
  return v.f;
}
__device__ __forceinline__ void split8(floatx4 a, floatx4 b, short8& hi, short8& lo) {
#pragma unroll
  for (int e = 0; e < 4; ++e) {
    unsigned short h0 = f2bf(a[e]);
    hi[e] = (short)h0;
    lo[e] = (short)f2bf(a[e] - bf2f(h0));
    unsigned short h1 = f2bf(b[e]);
    hi[e + 4] = (short)h1;
    lo[e + 4] = (short)f2bf(b[e] - bf2f(h1));
  }
}

// IC-scope (cross-XCD safe) relaxed atomic 8B store: sc0 sc1, bypasses L2
__device__ __forceinline__ void ic_store(unsigned short* p, unsigned long long v) {
  __hip_atomic_store((unsigned long long*)p, v, __ATOMIC_RELAXED,
                     __HIP_MEMORY_SCOPE_AGENT);
}

// 16 x 16B h-fragment loads + waitcnt in ONE asm block (outputs defined only at
// asm end -> compiler cannot schedule uses before the waitcnt). SC selects
// "sc0" (XCD-local L2) or "sc0 sc1" (IC, cross-XCD safe).
#define LOADA16(SC)                                                        \
  asm volatile("global_load_dwordx4 %0, %16, off " SC "\n\t"               \
               "global_load_dwordx4 %1, %16, off offset:64 " SC "\n\t"     \
               "global_load_dwordx4 %2, %16, off offset:128 " SC "\n\t"    \
               "global_load_dwordx4 %3, %16, off offset:192 " SC "\n\t"    \
               "global_load_dwordx4 %4, %16, off offset:256 " SC "\n\t"    \
               "global_load_dwordx4 %5, %16, off offset:320 " SC "\n\t"    \
               "global_load_dwordx4 %6, %16, off offset:384 " SC "\n\t"    \
               "global_load_dwordx4 %7, %16, off offset:448 " SC "\n\t"    \
               "global_load_dwordx4 %8, %17, off " SC "\n\t"               \
               "global_load_dwordx4 %9, %17, off offset:64 " SC "\n\t"     \
               "global_load_dwordx4 %10, %17, off offset:128 " SC "\n\t"   \
               "global_load_dwordx4 %11, %17, off offset:192 " SC "\n\t"   \
               "global_load_dwordx4 %12, %17, off offset:256 " SC "\n\t"   \
               "global_load_dwordx4 %13, %17, off offset:320 " SC "\n\t"   \
               "global_load_dwordx4 %14, %17, off offset:384 " SC "\n\t"   \
               "global_load_dwordx4 %15, %17, off offset:448 " SC "\n\t"   \
               "s_waitcnt vmcnt(0)"                                        \
               : "=&v"(A0[0]), "=&v"(A0[1]), "=&v"(A0[2]), "=&v"(A0[3]),   \
                 "=&v"(A0[4]), "=&v"(A0[5]), "=&v"(A0[6]), "=&v"(A0[7]),   \
                 "=&v"(A1[0]), "=&v"(A1[1]), "=&v"(A1[2]), "=&v"(A1[3]),   \
                 "=&v"(A1[4]), "=&v"(A1[5]), "=&v"(A1[6]), "=&v"(A1[7])    \
               : "v"(p0), "v"(p1)                                          \
               : "memory")

// E2[v][k] = sum_h embed[v][h] * Wxh[k][h]   (128 x 1024), near-fp32 via hi/lo
__global__ __launch_bounds__(64) void e2_kernel(const float* __restrict__ embed,
                                                const float* __restrict__ Wxh,
                                                float* __restrict__ E2) {
  const int lane = threadIdx.x;
  const int quad = lane >> 4, l16 = lane & 15;
  const int n0 = blockIdx.x * 16;
  floatx4 acc[8] = {};
  for (int ki = 0; ki < 32; ++ki) {
    const int k0 = ki * 32 + quad * 8;
    const float* bp = Wxh + (size_t)(n0 + l16) * Hdim + k0;
    floatx4 b0 = *(const floatx4*)bp;
    floatx4 b1 = *(const floatx4*)(bp + 4);
    short8 bhi, blo;
    split8(b0, b1, bhi, blo);
#pragma unroll
    for (int mi = 0; mi < 8; ++mi) {
      const float* ap = embed + (size_t)(mi * 16 + l16) * Hdim + k0;
      floatx4 a0 = *(const floatx4*)ap;
      floatx4 a1 = *(const floatx4*)(ap + 4);
      short8 ahi, alo;
      split8(a0, a1, ahi, alo);
      acc[mi] = MFMA_BF16(ahi, bhi, acc[mi]);
      acc[mi] = MFMA_BF16(ahi, blo, acc[mi]);
      acc[mi] = MFMA_BF16(alo, bhi, acc[mi]);
    }
  }
#pragma unroll
  for (int mi = 0; mi < 8; ++mi)
#pragma unroll
    for (int r = 0; r < 4; ++r)
      E2[(size_t)(mi * 16 + quad * 4 + r) * Hdim + n0 + l16] = acc[mi][r];
}

template <bool LOCAL>
__device__ __forceinline__ void rnn_loop(
    const int* __restrict__ xg, const float* __restrict__ fc_b,
    unsigned short* hb0, unsigned short* hb1, int* gflags, int* myflag,
    float* __restrict__ dout, short8 (&Bhi)[2][8], short8 (&Blo)[2][8],
    float (&e2s)[Vdim][NB + 1], float (&redc)[4][MB][NB + 1],
    float (&redf)[4][MB][17], unsigned short (&fcs)[VB][Hdim + 8],
    float (&bias2)[NB], int (&xi)[MB], int tid, int w, int lane, int quad,
    int l16, int r0, int n0, int v0) {
#pragma unroll 1
  for (int t = 0; t <= Sdim; ++t) {
    if (t < Sdim && tid < MB) xi[tid] = xg[(size_t)(r0 + tid) * Sdim + t];

    // wait: all group blocks must have published h_{t-1} (flag >= t).
    // Flags are ALWAYS IC-scope relaxed atomics (replay-safe, round-3 proven).
    if (t >= 1 && w == 0) {
      const int target = t;
      for (;;) {
        int v = (lane < NBLK)
                    ? __hip_atomic_load(gflags + lane * FPAD, __ATOMIC_RELAXED,
                                        __HIP_MEMORY_SCOPE_AGENT)
                    : target;
        if (__all(v >= target)) break;
        __builtin_amdgcn_s_sleep(1);
      }
    }
    __syncthreads();
    __atomic_signal_fence(__ATOMIC_SEQ_CST);

    if (t >= 1) {
      const unsigned short* hp = ((t - 1) & 1) ? hb1 : hb0;
      const bool recc = (t < Sdim);
      floatx4 accr[2][2] = {};
      floatx4 accf[2] = {};
      const unsigned short* p0 = hp + (size_t)(r0 + l16) * Hdim + w * 256 + quad * 8;
      const unsigned short* p1 = hp + (size_t)(r0 + 16 + l16) * Hdim + w * 256 + quad * 8;
      short8 A0[8], A1[8];
      if (LOCAL) {
        LOADA16("sc0");          // XCD-local: bypass L1, hit shared L2
      } else {
        LOADA16("sc0 sc1");      // cross-XCD: bypass L2, read IC
      }
#pragma unroll
      for (int ki = 0; ki < 8; ++ki) {
        short8 a0 = A0[ki], a1 = A1[ki];
        if (recc) {
          accr[0][0] = MFMA_BF16(a0, Bhi[0][ki], accr[0][0]);
          accr[0][0] = MFMA_BF16(a0, Blo[0][ki], accr[0][0]);
          accr[1][0] = MFMA_BF16(a1, Bhi[0][ki], accr[1][0]);
          accr[1][0] = MFMA_BF16(a1, Blo[0][ki], accr[1][0]);
          accr[0][1] = MFMA_BF16(a0, Bhi[1][ki], accr[0][1]);
          accr[0][1] = MFMA_BF16(a0, Blo[1][ki], accr[0][1]);
          accr[1][1] = MFMA_BF16(a1, Bhi[1][ki], accr[1][1]);
          accr[1][1] = MFMA_BF16(a1, Blo[1][ki], accr[1][1]);
        }
        short8 bf = *(const short8*)(&fcs[l16 & 3][w * 256 + ki * 32 + quad * 8]);
        accf[0] = MFMA_BF16(a0, bf, accf[0]);
        accf[1] = MFMA_BF16(a1, bf, accf[1]);
      }
      if (recc) {
#pragma unroll
        for (int mi = 0; mi < 2; ++mi)
#pragma unroll
          for (int ni = 0; ni < 2; ++ni)
#pragma unroll
            for (int r = 0; r < 4; ++r)
              redc[w][mi * 16 + quad * 4 + r][ni * 16 + l16] = accr[mi][ni][r];
      }
#pragma unroll
      for (int mi = 0; mi < 2; ++mi)
#pragma unroll
        for (int r = 0; r < 4; ++r)
          redf[w][mi * 16 + quad * 4 + r][l16] = accf[mi][r];
    }
    __syncthreads();

    // epilogue: h_t = tanh(E2[x] + bias + h@Whh^T); 4 neurons/thread, 8B store
    if (t < Sdim) {
      unsigned short* hw = (t & 1) ? hb1 : hb0;
      const int m = tid >> 3, nl0 = (tid & 7) * 4;
      float hv[4];
      union { unsigned short us[4]; unsigned long long q; } pk;
#pragma unroll
      for (int e = 0; e < 4; ++e) {
        int nl = nl0 + e;
        float s = e2s[xi[m]][nl] + bias2[nl];
        if (t >= 1)
          s += redc[0][m][nl] + redc[1][m][nl] + redc[2][m][nl] + redc[3][m][nl];
        hv[e] = tanhf(s);
        pk.us[e] = f2bf(hv[e]);
      }
      unsigned short* hdst = hw + (size_t)(r0 + m) * Hdim + n0 + nl0;
      if (LOCAL)
        *(unsigned long long*)hdst = pk.q;  // write-through -> shared XCD L2
      else
        ic_store(hdst, pk.q);
      if (t == Sdim - 1) {
#pragma unroll
        for (int e = 0; e < 4; ++e)
          dout[(size_t)Bdim * Sdim * Vdim + (size_t)(r0 + m) * Hdim + n0 + nl0 + e] = hv[e];
      }
    }
    // publish: __syncthreads drains vmcnt(0) per wave (h stores acked at L2/IC)
    // before the barrier; then one IC-scope relaxed flag store.
    if (t < Sdim) {
      __syncthreads();
      __atomic_signal_fence(__ATOMIC_SEQ_CST);
      if (tid == 0)
        __hip_atomic_store(myflag, t + 1, __ATOMIC_RELAXED, __HIP_MEMORY_SCOPE_AGENT);
    }
    // out[:, t-1, v-slice] = h_{t-1} @ fc^T + fc_b  (local data, after signal)
    if (t >= 1 && tid < MB * VB) {
      int m = tid >> 2, vv = tid & 3;
      float o = redf[0][m][vv] + redf[1][m][vv] + redf[2][m][vv] + redf[3][m][vv] + fc_b[v0 + vv];
      dout[((size_t)(r0 + m) * Sdim + (t - 1)) * Vdim + v0 + vv] = o;
    }
  }
}

__global__ __launch_bounds__(256, 1) void rnn_kernel(
    const int* __restrict__ xg, const float* __restrict__ Whh,
    const float* __restrict__ Wxh_b, const float* __restrict__ Whh_b,
    const float* __restrict__ fc_w, const float* __restrict__ fc_b,
    const float* __restrict__ E2, unsigned short* __restrict__ hbuf,
    int* __restrict__ flags, int* __restrict__ xcds, float* __restrict__ dout) {
  __shared__ float e2s[Vdim][NB + 1];
  __shared__ float redc[4][MB][NB + 1];
  __shared__ float redf[4][MB][17];
  __shared__ unsigned short fcs[VB][Hdim + 8];
  __shared__ float bias2[NB];
  __shared__ int xi[MB];
  __shared__ int sh_mode;

  const int tid = threadIdx.x;
  const int w = tid >> 6, lane = tid & 63;
  const int quad = lane >> 4, l16 = lane & 15;
  const int bid = blockIdx.x;
  const int g = bid & 7, j = bid >> 3;   // FIXED grouping (round-3 proven)
  const int r0 = g * MB, n0 = j * NB, v0 = j * VB;
  int* gflags = flags + g * NBLK * FPAD;
  int* myflag = gflags + j * FPAD;

  // 1) publish my physical XCD id (IC atomics; memset-visible, replay-safe)
  if (tid == 0) {
    int xcc = (int)(__builtin_amdgcn_s_getreg((3 << 11) | 20) & 7);  // HW_REG_XCC_ID
    __hip_atomic_store(xcds + g * NBLK + j, xcc + 1, __ATOMIC_RELAXED,
                       __HIP_MEMORY_SCOPE_AGENT);
  }

  // 2) preload Whh slice as hi/lo bf16 MFMA fragments (reused 256 steps)
  short8 Bhi[2][8], Blo[2][8];
#pragma unroll
  for (int ni = 0; ni < 2; ++ni)
#pragma unroll
    for (int ki = 0; ki < 8; ++ki) {
      const int n = n0 + ni * 16 + l16;
      const int k0 = w * 256 + ki * 32 + quad * 8;
      const float* p = Whh + (size_t)n * Hdim + k0;
      floatx4 f0 = *(const floatx4*)p;
      floatx4 f1 = *(const floatx4*)(p + 4);
      split8(f0, f1, Bhi[ni][ki], Blo[ni][ki]);
    }
  for (int i = tid; i < VB * Hdim; i += 256) {
    int r = i >> 10, c = i & (Hdim - 1);
    fcs[r][c] = f2bf(fc_w[(size_t)(v0 + r) * Hdim + c]);
  }
  for (int i = tid; i < Vdim * NB; i += 256) {
    int v = i >> 5, nl = i & 31;
    e2s[v][nl] = E2[(size_t)v * Hdim + n0 + nl];
  }
  if (tid < NB) bias2[tid] = Wxh_b[n0 + tid] + Whh_b[n0 + tid];

  // 3) per-GROUP registration: poll my group's 32 xcd ids (same wait pattern
  //    as the per-step barrier — no global rendezvous, deadlock-safe).
  //    LOCAL mode iff all 32 blocks of this group sit on one physical XCD.
  if (w == 0) {
    int v;
    for (;;) {
      v = __hip_atomic_load(xcds + g * NBLK + (lane & 31), __ATOMIC_RELAXED,
                            __HIP_MEMORY_SCOPE_AGENT);
      if (__all(v != 0)) break;
      __builtin_amdgcn_s_sleep(1);
    }
    int x0 = __shfl(v, 0);
    bool eq = __all(v == x0);
    if (lane == 0) sh_mode = eq ? 1 : 0;
  }
  __syncthreads();
  const bool local_mode = (sh_mode != 0);

  unsigned short* hb0 = hbuf;
  unsigned short* hb1 = hbuf + (size_t)Bdim * Hdim;

  if (local_mode)
    rnn_loop<true>(xg, fc_b, hb0, hb1, gflags, myflag, dout, Bhi, Blo, e2s,
                   redc, redf, fcs, bias2, xi, tid, w, lane, quad, l16, r0, n0, v0);
  else
    rnn_loop<false>(xg, fc_b, hb0, hb1, gflags, myflag, dout, Bhi, Blo, e2s,
                    redc, redf, fcs, bias2, xi, tid, w, lane, quad, l16, r0, n0, v0);
}

extern "C" void kernel_launch(void* const* d_in, const int* in_sizes, int n_in,
                              void* d_out, int out_size, void* d_ws, size_t ws_size,
                              hipStream_t stream) {
  const int* x = (const int*)d_in[0];
  const float* embed = (const float*)d_in[1];
  const float* Wxh_w = (const float*)d_in[2];
  const float* Wxh_b = (const float*)d_in[3];
  const float* Whh_w = (const float*)d_in[4];
  const float* Whh_b = (const float*)d_in[5];
  const float* fc_w = (const float*)d_in[6];
  const float* fc_b = (const float*)d_in[7];
  float* out = (float*)d_out;

  char* ws = (char*)d_ws;
  float* E2 = (float*)ws;                                   // 512 KB
  unsigned short* hbuf = (unsigned short*)(ws + 524288);    // 1 MB
  int* flags = (int*)(ws + 1572864);                        // 256 x 256B = 64 KB
  int* xcds = (int*)(ws + 1572864 + 65536);                 // 256 ints

  hipMemsetAsync(flags, 0, 256 * FPAD * sizeof(int) + 256 * sizeof(int), stream);
  e2_kernel<<<dim3(Hdim / 16), dim3(64), 0, stream>>>(embed, Wxh_w, E2);
  rnn_kernel<<<dim3(256), dim3(256), 0, stream>>>(x, Whh_w, Wxh_b, Whh_b, fc_w,
                                                  fc_b, E2, hbuf, flags, xcds, out);
}